// Round 2
// baseline (578.202 us; speedup 1.0000x reference)
//
#include <hip/hip_runtime.h>
#include <stdint.h>

// CoedgeConvLayer: out = relu(f@Ws + f[ni]@Wn + f[pi]@Wp + f[mi]@Wm + sum_b)
// R2: pipelined gathered GEMM. Per phase: [load B slice to regs (older in vmcnt)]
// [issue next phase's global_load_lds gathers (younger)] [compute] [barrier drains
// exactly the gathers]. idx reads are scalar loads (lgkmcnt) so they never force a
// vector drain. Two separate __shared__ buffers so AA can't invent a vmcnt(0)
// between gather-writes (buf A) and ds_reads (buf B).

#define D 256
#define BM 64

typedef __bf16 bf16x8 __attribute__((ext_vector_type(8)));
typedef float f32x4 __attribute__((ext_vector_type(4)));

static __device__ __forceinline__ uint16_t f32_to_bf16_rne(uint32_t u) {
    return (uint16_t)((u + 0x7FFFu + ((u >> 16) & 1u)) >> 16);
}

// ---------- fused prep: conv (all blocks) + W pack (blocks 0..127) + bias (block 128) ----------
__global__ void k_prep(const float* __restrict__ f, uint16_t* __restrict__ o, long total,
                       const float* __restrict__ Ws, const float* __restrict__ Wn,
                       const float* __restrict__ Wp, const float* __restrict__ Wm,
                       uint16_t* __restrict__ Bp,
                       const float* __restrict__ b0, const float* __restrict__ b1,
                       const float* __restrict__ b2, const float* __restrict__ b3,
                       float* __restrict__ btot) {
    long i = ((long)blockIdx.x * blockDim.x + threadIdx.x) * 8;
    if (i + 8 <= total) {
        const uint32_t* p = (const uint32_t*)(f + i);
        uint32_t v[8];
        *(uint4*)(v)     = *(const uint4*)(p);
        *(uint4*)(v + 4) = *(const uint4*)(p + 4);
        union { uint16_t u16[8]; uint4 v4; } r;
#pragma unroll
        for (int j = 0; j < 8; j++) r.u16[j] = f32_to_bf16_rne(v[j]);
        *(uint4*)(o + i) = r.v4;
    }
    if (blockIdx.x < 128) {
        // pack W_cat [1024,256] -> MFMA B-fragment layout (as R1 k_pack, 4 units/block)
        int b = blockIdx.x * 4 + (threadIdx.x >> 6);   // 0..511 = ksg*16 + nt
        int l = threadIdx.x & 63;
        int ksg = b >> 4, nt = b & 15;
        int ph = ksg >> 3;
        const float* W = (ph == 0) ? Ws : (ph == 1) ? Wn : (ph == 2) ? Wp : Wm;
        int kl = (ksg & 7) * 32 + (l >> 4) * 8;
        int n  = nt * 16 + (l & 15);
        uint16_t* dst = Bp + ((size_t)b * 64 + l) * 8;
#pragma unroll
        for (int j = 0; j < 8; j++) {
            uint32_t u = __builtin_bit_cast(uint32_t, W[(size_t)(kl + j) * D + n]);
            dst[j] = f32_to_bf16_rne(u);
        }
    } else if (blockIdx.x == 128) {
        int t = threadIdx.x;
        if (t < D) btot[t] = b0[t] + b1[t] + b2[t] + b3[t];
    }
}

// ---------- pipelined gathered GEMM ----------
typedef __attribute__((address_space(1))) uint32_t gu32;
typedef __attribute__((address_space(3))) uint32_t lu32;

// Gather 64 bf16 rows (phase p) into buf via global_load_lds, 2 rows/issue.
// idx values fetched as wave-uniform scalar loads (lgkmcnt, not vmcnt).
static __device__ __forceinline__ void stage(const uint16_t* __restrict__ fb,
                                             const int* __restrict__ idx,
                                             int m0, int w, int l,
                                             uint16_t* buf, int nrows) {
#pragma unroll
    for (int e = 0; e < 8; e++) {
        int rr = w * 16 + e * 2;                 // wave-uniform row-pair base
        int i0 = m0 + rr;
        if (i0 + 1 >= nrows) i0 = nrows - 2;     // safety (grid is exact for n=200000)
        int g0 = idx ? idx[i0]     : i0;         // uniform addr -> s_load
        int g1 = idx ? idx[i0 + 1] : i0 + 1;
        int hi = (l >> 5) & 1;
        int gr = hi ? g1 : g0;
        int r  = rr + hi;
        int cc = (l & 31) ^ (r & 7);             // fetch-side bank swizzle
        const uint16_t* g = fb + (size_t)gr * D + cc * 8;
        uint16_t* s = buf + rr * D;              // wave-uniform LDS base, +lane*16
        __builtin_amdgcn_global_load_lds((gu32*)g, (lu32*)s, 16, 0, 0);
    }
}

__global__ __launch_bounds__(256, 2) void k_gemm(
    const uint16_t* __restrict__ fb,
    const int* __restrict__ ni, const int* __restrict__ pi, const int* __restrict__ mi,
    const uint16_t* __restrict__ Bp, const float* __restrict__ btot,
    float* __restrict__ out, int nrows)
{
    __shared__ __align__(16) uint16_t As0[BM * D];   // 32 KB
    __shared__ __align__(16) uint16_t As1[BM * D];   // 32 KB
    const int t  = threadIdx.x;
    const int w  = t >> 6;
    const int l  = t & 63;
    const int ml = l & 15;
    const int q  = l >> 4;
    const int m0 = blockIdx.x * BM;

    f32x4 acc[4][4] = {};                        // 64 VGPRs
    bf16x8 Breg[32];                             // 128 VGPRs, one phase's B slice

    const uint16_t* bwave = Bp + (((size_t)w * 4) * 64 + l) * 8;

#define LOADB(p)                                                        \
    {                                                                   \
        const uint16_t* bb = bwave + (size_t)(p) * 128 * 64 * 8;        \
        _Pragma("unroll")                                               \
        for (int ks = 0; ks < 8; ks++)                                  \
            _Pragma("unroll")                                           \
            for (int j = 0; j < 4; j++)                                 \
                Breg[ks * 4 + j] =                                      \
                    *(const bf16x8*)(bb + ((size_t)(ks * 16 + j)) * 64 * 8); \
    }

#define COMPUTE(buf)                                                    \
    {                                                                   \
        _Pragma("unroll")                                               \
        for (int ks = 0; ks < 8; ks++) {                                \
            bf16x8 afr[4];                                              \
            _Pragma("unroll")                                           \
            for (int mt = 0; mt < 4; mt++) {                            \
                int r  = mt * 16 + ml;                                  \
                int ch = (ks * 4 + q) ^ (r & 7);                        \
                afr[mt] = *(const bf16x8*)&(buf)[r * D + ch * 8];       \
            }                                                           \
            _Pragma("unroll")                                           \
            for (int mt = 0; mt < 4; mt++)                              \
                _Pragma("unroll")                                       \
                for (int j = 0; j < 4; j++)                             \
                    acc[mt][j] = __builtin_amdgcn_mfma_f32_16x16x32_bf16( \
                        afr[mt], Breg[ks * 4 + j], acc[mt][j], 0, 0, 0);\
        }                                                               \
    }

    // prologue: both initial gathers in flight together
    stage(fb, (const int*)0, m0, w, l, As0, nrows);   // phase 0 (self)
    stage(fb, ni,            m0, w, l, As1, nrows);   // phase 1
    __syncthreads();                                   // drains both

    LOADB(0); COMPUTE(As0);
    __syncthreads();                                   // As0 reads done
    LOADB(1); stage(fb, pi, m0, w, l, As0, nrows); COMPUTE(As1);
    __syncthreads();                                   // drains phase-2 gathers; As1 free
    LOADB(2); stage(fb, mi, m0, w, l, As1, nrows); COMPUTE(As0);
    __syncthreads();                                   // drains phase-3 gathers
    LOADB(3); COMPUTE(As1);

    // epilogue: C/D layout col=lane&15, row=(lane>>4)*4+reg
#pragma unroll
    for (int j = 0; j < 4; j++) {
        int n = (w * 4 + j) * 16 + ml;
        float bv = btot[n];
#pragma unroll
        for (int mt = 0; mt < 4; mt++) {
#pragma unroll
            for (int rg = 0; rg < 4; rg++) {
                int row = m0 + mt * 16 + q * 4 + rg;
                if (row < nrows) {
                    float v = acc[mt][j][rg] + bv;
                    out[(size_t)row * D + n] = v > 0.f ? v : 0.f;
                }
            }
        }
    }
#undef LOADB
#undef COMPUTE
}

// ---------- fallback (ws too small): naive fp32 ----------
__global__ void k_naive(const float* __restrict__ f,
                        const int* __restrict__ ni, const int* __restrict__ pi,
                        const int* __restrict__ mi,
                        const float* __restrict__ Ws, const float* __restrict__ bs,
                        const float* __restrict__ Wn, const float* __restrict__ bn,
                        const float* __restrict__ Wp, const float* __restrict__ bp,
                        const float* __restrict__ Wm, const float* __restrict__ bm,
                        float* __restrict__ out) {
    int row = blockIdx.x, n = threadIdx.x;
    const float* f0 = f + (size_t)row * D;
    const float* f1 = f + (size_t)ni[row] * D;
    const float* f2 = f + (size_t)pi[row] * D;
    const float* f3 = f + (size_t)mi[row] * D;
    float s = bs[n] + bn[n] + bp[n] + bm[n];
    for (int k = 0; k < D; k++)
        s += f0[k] * Ws[k * D + n] + f1[k] * Wn[k * D + n] +
             f2[k] * Wp[k * D + n] + f3[k] * Wm[k * D + n];
    out[(size_t)row * D + n] = s > 0.f ? s : 0.f;
}

extern "C" void kernel_launch(void* const* d_in, const int* in_sizes, int n_in,
                              void* d_out, int out_size, void* d_ws, size_t ws_size,
                              hipStream_t stream) {
    const float* feat = (const float*)d_in[0];
    const int*   ni   = (const int*)d_in[1];
    const int*   pi   = (const int*)d_in[2];
    const int*   mi   = (const int*)d_in[3];
    const float* Ws   = (const float*)d_in[4];
    const float* bs   = (const float*)d_in[5];
    const float* Wn   = (const float*)d_in[6];
    const float* bn   = (const float*)d_in[7];
    const float* Wp   = (const float*)d_in[8];
    const float* bp   = (const float*)d_in[9];
    const float* Wm   = (const float*)d_in[10];
    const float* bm   = (const float*)d_in[11];
    float* out = (float*)d_out;

    int nrows = in_sizes[1];
    size_t feat_elems = (size_t)nrows * D;
    size_t fb_bytes   = feat_elems * 2;
    size_t bp_off     = fb_bytes;                 // 16B aligned (nrows*512)
    size_t bias_off   = bp_off + (size_t)1024 * D * 2;
    size_t need       = bias_off + (size_t)D * 4;

    if (ws_size < need) {
        k_naive<<<nrows, D, 0, stream>>>(feat, ni, pi, mi, Ws, bs, Wn, bn, Wp, bp, Wm, bm, out);
        return;
    }

    uint16_t* fbuf = (uint16_t*)d_ws;
    uint16_t* Bpk  = (uint16_t*)((char*)d_ws + bp_off);
    float*    btot = (float*)((char*)d_ws + bias_off);

    long total = (long)feat_elems;
    int cblocks = (int)((total / 8 + 255) / 256);
    if (cblocks < 129) cblocks = 129;
    k_prep<<<cblocks, 256, 0, stream>>>(feat, fbuf, total, Ws, Wn, Wp, Wm, Bpk,
                                        bs, bn, bp, bm, btot);
    k_gemm<<<(nrows + BM - 1) / BM, 256, 0, stream>>>(fbuf, ni, pi, mi, Bpk, btot, out, nrows);
}